// Round 1
// baseline (8771.944 us; speedup 1.0000x reference)
//
#include <hip/hip_runtime.h>
#include <math.h>

namespace {

constexpr int kB = 512;
constexpr int kL = 128;
constexpr int kD = 128;
constexpr int kSteps = 126;   // L - 2

// ---- workspace layout (float offsets) ----
constexpr size_t OFF_WT   = 0;                       // [256][512] concat(w_ih^T, w_hh^T)
constexpr size_t OFF_BIAS = 131072;                  // [512] b_ih + b_hh
constexpr size_t OFF_WQTG = 131584;                  // [128][128] wq_g^T
constexpr size_t OFF_WQTP = 147968;                  // wq_p^T
constexpr size_t OFF_WRTG = 164352;                  // wr_g^T
constexpr size_t OFF_WRTP = 180736;                  // wr_p^T
constexpr size_t OFF_REFG = 197120;                  // [L][B][D]
constexpr size_t OFF_REFP = OFF_REFG + (size_t)kL * kB * kD;

constexpr size_t OUT_IDX_OFF = (size_t)kSteps * kB * kL;  // probs first, then idx

// ---- dynamic LDS layout for decode_main (float offsets) ----
constexpr int SM_WQTG = 0;       // 16384
constexpr int SM_WQTP = 16384;   // 16384
constexpr int SM_XH   = 32768;   // [256][2]  k-major, bb inner (x in k<128, h in k>=128)
constexpr int SM_C    = 33280;   // [2][128]
constexpr int SM_GATES= 33536;   // [2][512]
constexpr int SM_RED  = 34560;   // [2048] reduction scratch
constexpr int SM_Q    = 36608;   // [2][128]
constexpr int SM_U    = 36864;   // [2][128]
constexpr int SM_P    = 37120;   // [2][128]
constexpr int SM_GV   = 37376;   // [2][128] glimpse vector
constexpr int SM_MASK = 37632;   // [2][128]
constexpr int SM_BIAS = 37888;   // [512]
constexpr int SM_VG   = 38400;
constexpr int SM_VP   = 38528;
constexpr int SM_BQG  = 38656;
constexpr int SM_BQP  = 38784;
constexpr int SM_IDX  = 38912;   // 2 ints (+ pad)
constexpr int SM_TOTAL= 38920;

__device__ __forceinline__ float sigf(float x) { return 1.0f / (1.0f + expf(-x)); }

} // namespace

// ---------- one-time: transposed weights + fused bias ----------
extern "C" __global__ void prep_weights(
    const float* __restrict__ w_ih, const float* __restrict__ w_hh,
    const float* __restrict__ b_ih, const float* __restrict__ b_hh,
    const float* __restrict__ wq_p, const float* __restrict__ wq_g,
    const float* __restrict__ wr_p, const float* __restrict__ wr_g,
    float* __restrict__ ws) {
  const int tid = blockIdx.x * blockDim.x + threadIdx.x;
  const int nth = gridDim.x * blockDim.x;
  for (int i = tid; i < 256 * 512; i += nth) {
    const int k = i >> 9, g = i & 511;
    ws[OFF_WT + i] = (k < 128) ? w_ih[g * 128 + k] : w_hh[g * 128 + (k - 128)];
  }
  for (int i = tid; i < 512; i += nth) ws[OFF_BIAS + i] = b_ih[i] + b_hh[i];
  for (int i = tid; i < 128 * 128; i += nth) {
    const int k = i >> 7, j = i & 127;
    ws[OFF_WQTG + i] = wq_g[j * 128 + k];
    ws[OFF_WQTP + i] = wq_p[j * 128 + k];
    ws[OFF_WRTG + i] = wr_g[j * 128 + k];
    ws[OFF_WRTP + i] = wr_p[j * 128 + k];
  }
}

// ---------- one-time: ref_p/ref_g = enc @ wr^T + br (1x1 conv hoisted) ----------
extern "C" __global__ __launch_bounds__(256) void prep_refs(
    const float* __restrict__ enc,
    const float* __restrict__ br_p, const float* __restrict__ br_g,
    float* __restrict__ ws) {
  extern __shared__ float lds[];
  float* s_wrTg = lds;             // 16384
  float* s_wrTp = lds + 16384;     // 16384
  float* s_enc  = lds + 32768;     // [2][128]
  float* ref_g = ws + OFF_REFG;
  float* ref_p = ws + OFF_REFP;
  const int t = threadIdx.x;
  for (int i = t; i < 16384; i += 256) {
    s_wrTg[i] = ws[OFF_WRTG + i];
    s_wrTp[i] = ws[OFF_WRTP + i];
  }
  __syncthreads();
  const int half = t >> 7, j = t & 127;
  const float brg = br_g[j], brp = br_p[j];
  const size_t base = (size_t)blockIdx.x * 64;
  for (int rr = 0; rr < 64; rr += 2) {
    const size_t rid = base + rr + half;   // rid = l*B + b
    s_enc[half * 128 + j] = enc[rid * 128 + j];
    __syncthreads();
    float ag = brg, ap = brp;
    #pragma unroll 8
    for (int k = 0; k < 128; ++k) {
      const float e = s_enc[half * 128 + k];
      ag += e * s_wrTg[k * 128 + j];
      ap += e * s_wrTp[k * 128 + j];
    }
    ref_g[rid * 128 + j] = ag;
    ref_p[rid * 128 + j] = ap;
    __syncthreads();
  }
}

// ---------- persistent decode: one block per 2 batch elements ----------
extern "C" __global__ __launch_bounds__(512) void decode_main(
    const float* __restrict__ dec0, const float* __restrict__ emb,
    const float* __restrict__ h0,   const float* __restrict__ c0,
    const float* __restrict__ enc,
    const float* __restrict__ bq_p, const float* __restrict__ v_p,
    const float* __restrict__ bq_g, const float* __restrict__ v_g,
    const float* __restrict__ ws, float* __restrict__ out) {
  extern __shared__ float sm[];
  float* s_wqTg = sm + SM_WQTG;
  float* s_wqTp = sm + SM_WQTP;
  int*   s_idx  = (int*)(sm + SM_IDX);
  const float* WT    = ws + OFF_WT;
  const float* ref_g = ws + OFF_REFG;
  const float* ref_p = ws + OFF_REFP;

  const int t  = threadIdx.x;
  const int b0 = blockIdx.x * 2;

  // one-time LDS fills
  for (int i = t; i < 16384; i += 512) {
    s_wqTg[i] = ws[OFF_WQTG + i];
    s_wqTp[i] = ws[OFF_WQTP + i];
  }
  sm[SM_BIAS + t] = ws[OFF_BIAS + t];
  if (t < 128) {
    sm[SM_VG  + t] = v_g[t];
    sm[SM_VP  + t] = v_p[t];
    sm[SM_BQG + t] = bq_g[t];
    sm[SM_BQP + t] = bq_p[t];
  }
  if (t < 256) {
    const int bb = t >> 7, d = t & 127, b = b0 + bb;
    sm[SM_XH + d * 2 + bb]         = dec0[b * 128 + d];   // x part
    sm[SM_XH + (128 + d) * 2 + bb] = h0[b * 128 + d];     // h part
    sm[SM_C + bb * 128 + d]        = c0[b * 128 + d];
    sm[SM_MASK + bb * 128 + d]     = (d < 2) ? 1.f : 0.f; // indices 0,1 pre-visited
  }
  __syncthreads();

  for (int step = 0; step < kSteps; ++step) {
    // ---- Phase L1: LSTM gates = [x;h] @ WT + bias (both b's share weight stream) ----
    {
      const int kh = t >> 8;         // k-half
      const int gl = t & 255;        // gate pair 2*gl, 2*gl+1
      float a00 = 0.f, a01 = 0.f, a10 = 0.f, a11 = 0.f;
      const float* wp = WT + (size_t)kh * 128 * 512 + 2 * gl;
      const float* xp = sm + SM_XH + kh * 128 * 2;
      #pragma unroll 8
      for (int kk = 0; kk < 128; ++kk) {
        const float2 w2 = *(const float2*)(wp + (size_t)kk * 512);
        const float2 x2 = *(const float2*)(xp + kk * 2);   // (x[k] for b0, b1) broadcast
        a00 += x2.x * w2.x; a01 += x2.x * w2.y;
        a10 += x2.y * w2.x; a11 += x2.y * w2.y;
      }
      *(float2*)(sm + SM_RED + (kh * 2 + 0) * 512 + 2 * gl) = make_float2(a00, a01);
      *(float2*)(sm + SM_RED + (kh * 2 + 1) * 512 + 2 * gl) = make_float2(a10, a11);
    }
    __syncthreads();
    {
      const int bb = t >> 8, g = t & 255;
      for (int gg = g; gg < 512; gg += 256) {
        sm[SM_GATES + bb * 512 + gg] = sm[SM_BIAS + gg]
            + sm[SM_RED + bb * 512 + gg] + sm[SM_RED + (2 + bb) * 512 + gg];
      }
    }
    __syncthreads();
    // ---- Phase L2: LSTM cell elementwise; mask update (use_prev only) ----
    if (t < 256) {
      const int bb = t >> 7, d = t & 127;
      const float gi = sm[SM_GATES + bb * 512 + d];
      const float gf = sm[SM_GATES + bb * 512 + 128 + d];
      const float gg = sm[SM_GATES + bb * 512 + 256 + d];
      const float go = sm[SM_GATES + bb * 512 + 384 + d];
      const float cc = sigf(gf) * sm[SM_C + bb * 128 + d] + sigf(gi) * tanhf(gg);
      const float hh = sigf(go) * tanhf(cc);
      sm[SM_C + bb * 128 + d] = cc;
      sm[SM_XH + (128 + d) * 2 + bb] = hh;
    }
    if (step > 0 && t < 2) sm[SM_MASK + t * 128 + s_idx[t]] = 1.f;
    __syncthreads();
    // ---- Phase A1: q_g = h @ wq_g^T + bq_g ----
    {
      const int kh2 = t >> 8, bb = (t >> 7) & 1, j = t & 127;
      float acc = 0.f;
      #pragma unroll 8
      for (int kk = 0; kk < 64; ++kk) {
        const int k = kh2 * 64 + kk;
        acc += sm[SM_XH + (128 + k) * 2 + bb] * s_wqTg[k * 128 + j];
      }
      sm[SM_RED + (kh2 * 2 + bb) * 128 + j] = acc;
    }
    __syncthreads();
    if (t < 256) {
      const int bb = t >> 7, j = t & 127;
      sm[SM_Q + bb * 128 + j] = sm[SM_BQG + j]
          + sm[SM_RED + bb * 128 + j] + sm[SM_RED + (2 + bb) * 128 + j];
    }
    __syncthreads();
    // ---- Phase A2: glimpse scores u_g[l] = v_g . tanh(ref_g + q_g) ----
    {
      const int wv = t >> 6, lane = t & 63, d0 = 2 * lane;
      for (int r = wv; r < 256; r += 8) {
        const int bb = r >> 7, l = r & 127;
        const float2 rf = *(const float2*)(ref_g + ((size_t)l * kB + b0 + bb) * kD + d0);
        float s = sm[SM_VG + d0]     * tanhf(rf.x + sm[SM_Q + bb * 128 + d0])
                + sm[SM_VG + d0 + 1] * tanhf(rf.y + sm[SM_Q + bb * 128 + d0 + 1]);
        #pragma unroll
        for (int off = 1; off < 64; off <<= 1) s += __shfl_xor(s, off, 64);
        if (lane == 0) {
          if (step > 0 && sm[SM_MASK + bb * 128 + l] != 0.f) s = -INFINITY;
          sm[SM_U + bb * 128 + l] = s;
        }
      }
    }
    __syncthreads();
    // ---- Phase A3: glimpse softmax (wave 0 -> b0, wave 1 -> b1) ----
    if (t < 128) {
      const int bb = t >> 6, lane = t & 63;
      const float v0 = sm[SM_U + bb * 128 + lane], v1 = sm[SM_U + bb * 128 + 64 + lane];
      float m = fmaxf(v0, v1);
      #pragma unroll
      for (int off = 1; off < 64; off <<= 1) m = fmaxf(m, __shfl_xor(m, off, 64));
      const float e0 = expf(v0 - m), e1 = expf(v1 - m);
      float ssum = e0 + e1;
      #pragma unroll
      for (int off = 1; off < 64; off <<= 1) ssum += __shfl_xor(ssum, off, 64);
      sm[SM_P + bb * 128 + lane]      = e0 / ssum;
      sm[SM_P + bb * 128 + 64 + lane] = e1 / ssum;
    }
    __syncthreads();
    // ---- Phase A4: glimpse readout g = p @ enc ----
    {
      const int lh = t >> 8, bb = (t >> 7) & 1, d = t & 127;
      float acc = 0.f;
      #pragma unroll 4
      for (int ll = 0; ll < 64; ++ll) {
        const int l = lh * 64 + ll;
        acc += sm[SM_P + bb * 128 + l] * enc[((size_t)l * kB + b0 + bb) * kD + d];
      }
      sm[SM_RED + (lh * 2 + bb) * 128 + d] = acc;
    }
    __syncthreads();
    if (t < 256) {
      const int bb = t >> 7, d = t & 127;
      sm[SM_GV + bb * 128 + d] = sm[SM_RED + bb * 128 + d] + sm[SM_RED + (2 + bb) * 128 + d];
    }
    __syncthreads();
    // ---- Phase A5: q_p = g @ wq_p^T + bq_p ----
    {
      const int kh2 = t >> 8, bb = (t >> 7) & 1, j = t & 127;
      float acc = 0.f;
      #pragma unroll 8
      for (int kk = 0; kk < 64; ++kk) {
        const int k = kh2 * 64 + kk;
        acc += sm[SM_GV + bb * 128 + k] * s_wqTp[k * 128 + j];
      }
      sm[SM_RED + (kh2 * 2 + bb) * 128 + j] = acc;
    }
    __syncthreads();
    if (t < 256) {
      const int bb = t >> 7, j = t & 127;
      sm[SM_Q + bb * 128 + j] = sm[SM_BQP + j]
          + sm[SM_RED + bb * 128 + j] + sm[SM_RED + (2 + bb) * 128 + j];
    }
    __syncthreads();
    // ---- Phase A6: pointer scores, clipped 10*tanh(u), masked ----
    {
      const int wv = t >> 6, lane = t & 63, d0 = 2 * lane;
      for (int r = wv; r < 256; r += 8) {
        const int bb = r >> 7, l = r & 127;
        const float2 rf = *(const float2*)(ref_p + ((size_t)l * kB + b0 + bb) * kD + d0);
        float s = sm[SM_VP + d0]     * tanhf(rf.x + sm[SM_Q + bb * 128 + d0])
                + sm[SM_VP + d0 + 1] * tanhf(rf.y + sm[SM_Q + bb * 128 + d0 + 1]);
        #pragma unroll
        for (int off = 1; off < 64; off <<= 1) s += __shfl_xor(s, off, 64);
        if (lane == 0) {
          float uu = 10.f * tanhf(s);
          if (step > 0 && sm[SM_MASK + bb * 128 + l] != 0.f) uu = -INFINITY;
          sm[SM_U + bb * 128 + l] = uu;
        }
      }
    }
    __syncthreads();
    // ---- Phase A7: pointer softmax + first-index argmax ----
    if (t < 128) {
      const int bb = t >> 6, lane = t & 63;
      const float v0 = sm[SM_U + bb * 128 + lane], v1 = sm[SM_U + bb * 128 + 64 + lane];
      float m = fmaxf(v0, v1);
      #pragma unroll
      for (int off = 1; off < 64; off <<= 1) m = fmaxf(m, __shfl_xor(m, off, 64));
      const float e0 = expf(v0 - m), e1 = expf(v1 - m);
      float ssum = e0 + e1;
      #pragma unroll
      for (int off = 1; off < 64; off <<= 1) ssum += __shfl_xor(ssum, off, 64);
      sm[SM_P + bb * 128 + lane]      = e0 / ssum;
      sm[SM_P + bb * 128 + 64 + lane] = e1 / ssum;
      float av; int ai;
      if (v0 >= v1) { av = v0; ai = lane; } else { av = v1; ai = lane + 64; }
      #pragma unroll
      for (int off = 1; off < 64; off <<= 1) {
        const float ov = __shfl_xor(av, off, 64);
        const int   oi = __shfl_xor(ai, off, 64);
        if (ov > av || (ov == av && oi < ai)) { av = ov; ai = oi; }
      }
      if (lane == 0) {
        s_idx[bb] = ai;
        out[OUT_IDX_OFF + (size_t)step * kB + b0 + bb] = (float)ai;
      }
    }
    __syncthreads();
    // ---- Phase A8: write probs row; gather next decoder input ----
    if (t < 256) {
      const int bb = t >> 7, d = t & 127, b = b0 + bb;
      out[((size_t)step * kB + b) * kL + d] = sm[SM_P + bb * 128 + d];
      const int idx = s_idx[bb];
      sm[SM_XH + d * 2 + bb] = emb[((size_t)idx * kB + b) * kD + d];
    }
    __syncthreads();
  }
}

extern "C" void kernel_launch(void* const* d_in, const int* in_sizes, int n_in,
                              void* d_out, int out_size, void* d_ws, size_t ws_size,
                              hipStream_t stream) {
  (void)in_sizes; (void)n_in; (void)out_size; (void)ws_size;
  const float* dec0 = (const float*)d_in[0];
  const float* emb  = (const float*)d_in[1];
  const float* h0   = (const float*)d_in[2];
  const float* c0   = (const float*)d_in[3];
  const float* enc  = (const float*)d_in[4];
  const float* w_ih = (const float*)d_in[5];
  const float* w_hh = (const float*)d_in[6];
  const float* b_ih = (const float*)d_in[7];
  const float* b_hh = (const float*)d_in[8];
  const float* wq_p = (const float*)d_in[9];
  const float* bq_p = (const float*)d_in[10];
  const float* wr_p = (const float*)d_in[11];
  const float* br_p = (const float*)d_in[12];
  const float* v_p  = (const float*)d_in[13];
  const float* wq_g = (const float*)d_in[14];
  const float* bq_g = (const float*)d_in[15];
  const float* wr_g = (const float*)d_in[16];
  const float* br_g = (const float*)d_in[17];
  const float* v_g  = (const float*)d_in[18];
  float* ws  = (float*)d_ws;
  float* out = (float*)d_out;

  prep_weights<<<dim3(64), dim3(256), 0, stream>>>(
      w_ih, w_hh, b_ih, b_hh, wq_p, wq_g, wr_p, wr_g, ws);
  prep_refs<<<dim3(1024), dim3(256), (32768 + 256) * 4, stream>>>(
      enc, br_p, br_g, ws);
  decode_main<<<dim3(256), dim3(512), SM_TOTAL * 4, stream>>>(
      dec0, emb, h0, c0, enc, bq_p, v_p, bq_g, v_g, ws, out);
}